// Round 1
// baseline (1673.143 us; speedup 1.0000x reference)
//
#include <hip/hip_runtime.h>
#include <math.h>

// Problem constants (setup_inputs: N=32, C=1, W=512, L=512)
#define WD 512          // image / detector width
#define PF 1024         // FFT pad length = 2^ceil(log2(2W))
#define LH2 1028        // shifted ramp-kernel table length (index r-m+512 in [1,1023], +pad)

// Workspace layout (float offsets). Requires ws_size >= (4128 + NC*WD*WD)*4 bytes (~33.6 MB).
#define OFF_H2 0
#define OFF_CS 1056
#define OFF_SN 1568
#define OFF_WA 2080
#define OFF_WB 2592
#define OFF_IA 3104
#define OFF_IB 3616
#define OFF_XF 4128     // filtered sinogram, transposed: [n][col][r], NC*WD*WD floats

// ---------------------------------------------------------------------------
// Setup: ramp kernel table h2[i] = h[(i-512) & 1023], per-angle trig, and the
// (generic) angle-interpolation parameters from the reference's cx/c0/wc path.
// ---------------------------------------------------------------------------
__global__ void setup_kernel(const float* __restrict__ theta,
                             float* __restrict__ ws, int L) {
  int gid = blockIdx.x * blockDim.x + threadIdx.x;
  if (gid < LH2) {
    int dd = gid - (PF / 2);
    if (dd < 0) dd = -dd;                   // h is even and periodic in d
    float acc = 0.f;
    for (int k = 0; k < PF; ++k) {
      int kk = (k <= PF / 2) ? k : (PF - k);
      float filt = 2.f * (float)kk * (1.f / (float)PF);   // 2*|fftfreq|
      int m = (k * dd) & (PF - 1);                        // arg mod 2pi, keeps cosf accurate
      float arg = (float)m * (6.28318530717958647692f / (float)PF);
      acc = fmaf(filt, cosf(arg), acc);
    }
    ws[OFF_H2 + gid] = acc * (1.f / (float)PF);
  } else if (gid < LH2 + L) {
    int l = gid - LH2;
    double rad = (double)theta[l] * 0.017453292519943295;
    ws[OFF_CS + l] = (float)cos(rad);
    ws[OFF_SN + l] = (float)sin(rad);
    // angle -> sinogram-column interpolation (identity when L == WD)
    float cx = (float)l * (float)((double)(WD - 1) / (double)(L - 1));
    float c0 = floorf(cx);
    float wc = cx - c0;
    int ia = (int)c0;
    int ib = ia + 1;
    float ok = (ib <= WD - 1) ? 1.f : 0.f;
    if (ib > WD - 1) ib = WD - 1;
    ws[OFF_WA + l] = 1.f - wc;
    ws[OFF_WB + l] = wc * ok;
    ((int*)ws)[OFF_IA + l] = ia;
    ((int*)ws)[OFF_IB + l] = ib;
  }
}

// ---------------------------------------------------------------------------
// Ramp filter as circular convolution, written TRANSPOSED:
//   xf_t[n][l][r] = sum_m x[n][m][l] * h2[r - m + 512]
// Block: 256 threads, C-tile 64(l) x 64(r), 4x4 microtile per thread.
// ---------------------------------------------------------------------------
__global__ __launch_bounds__(256) void filter_kernel(
    const float* __restrict__ x, const float* __restrict__ ws,
    float* __restrict__ xf_t) {
  __shared__ __align__(16) float h2l[LH2];
  __shared__ __align__(16) float bxl[64][68];   // [m][l], +4 pad keeps 16B rows / breaks conflicts
  const int t = threadIdx.x;
  const int n = blockIdx.y;
  const int rt = blockIdx.x & 7;
  const int lt = blockIdx.x >> 3;
  const int l0 = lt << 6, r0 = rt << 6;
  const int ty = t >> 4, tx = t & 15;

  for (int i = t; i < LH2; i += 256) h2l[i] = ws[OFF_H2 + i];

  float acc[4][4] = {};
  const float* __restrict__ xn = x + (size_t)n * WD * WD;

  for (int mc = 0; mc < WD; mc += 64) {
    __syncthreads();
#pragma unroll
    for (int q = 0; q < 4; ++q) {            // stage x[mc..mc+63][l0..l0+63]
      int fid = t + (q << 8);
      int row = fid >> 4;
      int c4 = (fid & 15) << 2;
      float4 v = *(const float4*)(xn + (size_t)(mc + row) * WD + l0 + c4);
      *(float4*)(&bxl[row][c4]) = v;
    }
    __syncthreads();
    const int rbase = r0 + (tx << 2) + (PF / 2) - mc;
#pragma unroll 4
    for (int m = 0; m < 64; ++m) {
      float4 bv = *(const float4*)(&bxl[m][ty << 2]);
      const float* hp = &h2l[rbase - m];
      float b[4] = {bv.x, bv.y, bv.z, bv.w};
      float a[4] = {hp[0], hp[1], hp[2], hp[3]};
#pragma unroll
      for (int li = 0; li < 4; ++li)
#pragma unroll
        for (int rj = 0; rj < 4; ++rj)
          acc[li][rj] = fmaf(b[li], a[rj], acc[li][rj]);
    }
  }
#pragma unroll
  for (int li = 0; li < 4; ++li) {
    float4 o = make_float4(acc[li][0], acc[li][1], acc[li][2], acc[li][3]);
    *(float4*)(xf_t + (size_t)(n * WD + l0 + (ty << 2) + li) * WD + r0 + (tx << 2)) = o;
  }
}

// ---------------------------------------------------------------------------
// Backprojection. Block: 256 threads = 64x64 pixel tile (4x4 px/thread) x 2
// batch images. Per angle: stage both projections into LDS interleaved
// [r][n] with zero guards at r=-1 and r=512 so boundary masking is free.
// ---------------------------------------------------------------------------
__global__ __launch_bounds__(256) void backproj_kernel(
    const float* __restrict__ ws, float* __restrict__ out, int L) {
  __shared__ __align__(16) float g2[1028];  // (514 guarded rows) x 2 images, interleaved
  const int t = threadIdx.x;
  const int tx = t & 15, ty = t >> 4;
  const int j0 = (blockIdx.x & 7) << 6;
  const int i0 = (blockIdx.x >> 3) << 6;
  const int n0 = blockIdx.y << 1;

  const float* __restrict__ xf = ws + OFF_XF;
  const float* __restrict__ cs = ws + OFF_CS;
  const float* __restrict__ sn = ws + OFF_SN;
  const float* __restrict__ wA = ws + OFF_WA;
  const float* __restrict__ wB = ws + OFF_WB;
  const int* __restrict__ iA = (const int*)ws + OFF_IA;
  const int* __restrict__ iB = (const int*)ws + OFF_IB;

  if (t < 2) { g2[t] = 0.f; g2[1026 + t] = 0.f; }   // guards, written once

  const int nloc = t >> 7;              // which of the 2 images this thread stages
  const int r4 = (t & 127) << 2;        // 4 detector samples per thread
  const float* stage_base = xf + (size_t)(n0 + nloc) * WD * WD + r4;

  float tiv[4], tjv[4];
#pragma unroll
  for (int a = 0; a < 4; ++a) {         // linspace(-1,1,512) values, fp64-exact then rounded
    tiv[a] = (float)(-1.0 + 2.0 * (double)(i0 + (ty << 2) + a) / (double)(WD - 1));
    tjv[a] = (float)(-1.0 + 2.0 * (double)(j0 + (tx << 2) + a) / (double)(WD - 1));
  }
  const float hw = 0.5f * (float)(WD - 1);
  float acc[4][4][2] = {};

  for (int l = 0; l < L; ++l) {
    float wAl = wA[l];
    float wBl = wB[l];
    float4 v = *(const float4*)(stage_base + (size_t)iA[l] * WD);
    if (wBl != 0.f) {                   // generic angle interp (never taken when L==WD)
      float4 v2 = *(const float4*)(stage_base + (size_t)iB[l] * WD);
      v.x = fmaf(v.x, wAl, v2.x * wBl);
      v.y = fmaf(v.y, wAl, v2.y * wBl);
      v.z = fmaf(v.z, wAl, v2.z * wBl);
      v.w = fmaf(v.w, wAl, v2.w * wBl);
    } else if (wAl != 1.f) {
      v.x *= wAl; v.y *= wAl; v.z *= wAl; v.w *= wAl;
    }
    float c = cs[l] * hw;
    float s = sn[l] * hw;
    __syncthreads();                    // previous iteration's compute done
    {
      int kb = ((r4 + 1) << 1) + nloc;  // interleaved, +1 for the r=-1 guard slot
      g2[kb] = v.x; g2[kb + 2] = v.y; g2[kb + 4] = v.z; g2[kb + 6] = v.w;
    }
    __syncthreads();
#pragma unroll
    for (int di = 0; di < 4; ++di) {
      float bi = fmaf(tiv[di], -s, hw);
#pragma unroll
      for (int dj = 0; dj < 4; ++dj) {
        float ry = fmaf(tjv[dj], c, bi);
        float r0f = floorf(ry);
        float w1 = ry - r0f;
        int r0i = (int)r0f;
        int idx = r0i < -1 ? -1 : (r0i > WD - 1 ? WD - 1 : r0i);
        bool valid = (r0i >= -1) && (r0i <= WD - 1);
        float wa = valid ? (1.f - w1) : 0.f;
        float wb = valid ? w1 : 0.f;
        int k0 = idx + 1;
        const float2* gp = (const float2*)g2;
        float2 q0 = gp[k0];             // tap r0 for both images
        float2 q1 = gp[k0 + 1];         // tap r0+1 for both images
        acc[di][dj][0] = fmaf(q0.x, wa, fmaf(q1.x, wb, acc[di][dj][0]));
        acc[di][dj][1] = fmaf(q0.y, wa, fmaf(q1.y, wb, acc[di][dj][1]));
      }
    }
  }

  const float scale = (float)(3.14159265358979323846 / (2.0 * (double)L));
#pragma unroll
  for (int nn = 0; nn < 2; ++nn) {
#pragma unroll
    for (int di = 0; di < 4; ++di) {
      float4 o;
      float* po = &o.x;
#pragma unroll
      for (int dj = 0; dj < 4; ++dj) {
        float rr = tiv[di] * tiv[di] + tjv[dj] * tjv[dj];
        float msk = (rr <= 1.f) ? scale : 0.f;
        po[dj] = acc[di][dj][nn] * msk;
      }
      *(float4*)(out + (size_t)((n0 + nn) * WD + i0 + (ty << 2) + di) * WD
                 + j0 + (tx << 2)) = o;
    }
  }
}

extern "C" void kernel_launch(void* const* d_in, const int* in_sizes, int n_in,
                              void* d_out, int out_size, void* d_ws, size_t ws_size,
                              hipStream_t stream) {
  const float* x = (const float*)d_in[0];
  const float* theta = (const float*)d_in[1];
  float* out = (float*)d_out;
  float* ws = (float*)d_ws;
  int L = in_sizes[1];                       // 512
  int NC = in_sizes[0] / (WD * WD);          // 32
  float* xf_t = ws + OFF_XF;

  int nset = LH2 + L;
  hipLaunchKernelGGL(setup_kernel, dim3((nset + 255) / 256), dim3(256), 0, stream,
                     theta, ws, L);
  hipLaunchKernelGGL(filter_kernel, dim3((WD / 64) * 8, NC), dim3(256), 0, stream,
                     x, ws, xf_t);
  hipLaunchKernelGGL(backproj_kernel, dim3(64, NC / 2), dim3(256), 0, stream,
                     ws, out, L);
}

// Round 3
// 942.598 us; speedup vs baseline: 1.7750x; 1.7750x over previous
//
#include <hip/hip_runtime.h>
#include <math.h>

// Problem constants (setup_inputs: N=32, C=1, W=512, L=512)
#define WD 512          // image / detector width
#define PF 1024         // FFT pad length = 2^ceil(log2(2W))
#define LH2 1028        // shifted ramp-kernel table length

// Workspace layout (float offsets). Requires ws_size >= (4128 + NC*WD*WD)*4 bytes (~33.6 MB).
#define OFF_H2 0
#define OFF_CS 1056
#define OFF_SN 1568
#define OFF_WA 2080
#define OFF_WB 2592
#define OFF_IA 3104
#define OFF_IB 3616
#define OFF_XF 4128     // filtered sinogram, transposed: [n][col][r]

#define GOFF 107        // LDS slot = detector_index + GOFF (guards absorb out-of-circle idx)
#define GSLOTS 726      // covers idx in [-107, 618]; valid data slots 107..618

typedef __fp16 half2_t __attribute__((ext_vector_type(2)));

__device__ __forceinline__ half2_t pkh(float a, float b) {
  return __builtin_amdgcn_cvt_pkrtz(a, b);   // v_cvt_pkrtz_f16_f32
}

__device__ __forceinline__ unsigned pkbits(float a, float b) {
  return __builtin_bit_cast(unsigned, pkh(a, b));
}

__device__ __forceinline__ float dot2f(unsigned tapbits, half2_t w, float c) {
  half2_t tp = __builtin_bit_cast(half2_t, tapbits);
  return __builtin_amdgcn_fdot2(tp, w, c, false);   // v_dot2_f32_f16
}

// ---------------------------------------------------------------------------
// Setup: ramp kernel table h2[i] = h[(i-512) & 1023], per-angle trig + interp.
// ---------------------------------------------------------------------------
__global__ void setup_kernel(const float* __restrict__ theta,
                             float* __restrict__ ws, int L) {
  int gid = blockIdx.x * blockDim.x + threadIdx.x;
  if (gid < LH2) {
    int dd = gid - (PF / 2);
    if (dd < 0) dd = -dd;
    float acc = 0.f;
    for (int k = 0; k < PF; ++k) {
      int kk = (k <= PF / 2) ? k : (PF - k);
      float filt = 2.f * (float)kk * (1.f / (float)PF);
      int m = (k * dd) & (PF - 1);
      float arg = (float)m * (6.28318530717958647692f / (float)PF);
      acc = fmaf(filt, cosf(arg), acc);
    }
    ws[OFF_H2 + gid] = acc * (1.f / (float)PF);
  } else if (gid < LH2 + L) {
    int l = gid - LH2;
    double rad = (double)theta[l] * 0.017453292519943295;
    ws[OFF_CS + l] = (float)cos(rad);
    ws[OFF_SN + l] = (float)sin(rad);
    float cx = (float)l * (float)((double)(WD - 1) / (double)(L - 1));
    float c0 = floorf(cx);
    float wc = cx - c0;
    int ia = (int)c0;
    int ib = ia + 1;
    float ok = (ib <= WD - 1) ? 1.f : 0.f;
    if (ib > WD - 1) ib = WD - 1;
    ws[OFF_WA + l] = 1.f - wc;
    ws[OFF_WB + l] = wc * ok;
    ((int*)ws)[OFF_IA + l] = ia;
    ((int*)ws)[OFF_IB + l] = ib;
  }
}

// ---------------------------------------------------------------------------
// Ramp filter as circular convolution, written TRANSPOSED:
//   xf_t[n][l][r] = sum_m x[n][m][l] * h2[r - m + 512]
// Rolling 4-reg h window: 1 ds_read_b32 per k-step instead of 4.
// ---------------------------------------------------------------------------
__global__ __launch_bounds__(256) void filter_kernel(
    const float* __restrict__ x, const float* __restrict__ ws,
    float* __restrict__ xf_t) {
  __shared__ __align__(16) float h2l[LH2];
  __shared__ __align__(16) float bxl[64][68];
  const int t = threadIdx.x;
  const int n = blockIdx.y;
  const int rt = blockIdx.x & 7;
  const int lt = blockIdx.x >> 3;
  const int l0 = lt << 6, r0 = rt << 6;
  const int ty = t >> 4, tx = t & 15;

  for (int i = t; i < LH2; i += 256) h2l[i] = ws[OFF_H2 + i];

  float acc[4][4] = {};
  const float* __restrict__ xn = x + (size_t)n * WD * WD;

  for (int mc = 0; mc < WD; mc += 64) {
    __syncthreads();
#pragma unroll
    for (int q = 0; q < 4; ++q) {
      int fid = t + (q << 8);
      int row = fid >> 4;
      int c4 = (fid & 15) << 2;
      float4 v = *(const float4*)(xn + (size_t)(mc + row) * WD + l0 + c4);
      *(float4*)(&bxl[row][c4]) = v;
    }
    __syncthreads();
    const int rbase = r0 + (tx << 2) + (PF / 2) - mc;
    float a0 = h2l[rbase], a1 = h2l[rbase + 1],
          a2 = h2l[rbase + 2], a3 = h2l[rbase + 3];
#pragma unroll 8
    for (int m = 0; m < 64; ++m) {
      float4 bv = *(const float4*)(&bxl[m][ty << 2]);
      float nh = h2l[rbase - m - 1];        // next window's low element
      float b[4] = {bv.x, bv.y, bv.z, bv.w};
#pragma unroll
      for (int li = 0; li < 4; ++li) {
        acc[li][0] = fmaf(b[li], a0, acc[li][0]);
        acc[li][1] = fmaf(b[li], a1, acc[li][1]);
        acc[li][2] = fmaf(b[li], a2, acc[li][2]);
        acc[li][3] = fmaf(b[li], a3, acc[li][3]);
      }
      a3 = a2; a2 = a1; a1 = a0; a0 = nh;   // slide window (reg rotate, free)
    }
  }
#pragma unroll
  for (int li = 0; li < 4; ++li) {
    float4 o = make_float4(acc[li][0], acc[li][1], acc[li][2], acc[li][3]);
    *(float4*)(xf_t + (size_t)(n * WD + l0 + (ty << 2) + li) * WD + r0 + (tx << 2)) = o;
  }
}

// ---------------------------------------------------------------------------
// Backprojection v2. Block: 256 threads, 64x64 pixel tile x 4 images.
// STRIDED microtile: j = j0 + tx + 16*dj, i = i0 + ty + 16*di  -> adjacent
// lanes are adjacent pixels -> LDS index delta per lane = cos(theta) <= 1
// -> ~2-way bank aliasing (free).
// LDS slot s (16B): [(h0[r],h0[r+1]),(h1..),(h2..),(h3..)] as 4x packed half2,
// r = s - GOFF, zero guards for out-of-circle indices -> no clamping.
// Per pixel: 1 ds_read_b128 + 4 v_dot2_f32_f16 serves 4 images.
// ---------------------------------------------------------------------------
__global__ __launch_bounds__(256) void backproj_kernel(
    const float* __restrict__ ws, float* __restrict__ out, int L) {
  __shared__ __align__(16) uint4 g[GSLOTS];
  const int t = threadIdx.x;
  const int tx = t & 15, ty = t >> 4;
  const int j0 = (blockIdx.x & 7) << 6;
  const int i0 = (blockIdx.x >> 3) << 6;
  const int n0 = blockIdx.y << 2;

  const float* __restrict__ xf = ws + OFF_XF;
  const float* __restrict__ cs = ws + OFF_CS;
  const float* __restrict__ sn = ws + OFF_SN;
  const float* __restrict__ wA = ws + OFF_WA;
  const float* __restrict__ wB = ws + OFF_WB;
  const int* __restrict__ iA = (const int*)ws + OFF_IA;
  const int* __restrict__ iB = (const int*)ws + OFF_IB;

  for (int s = t; s < GSLOTS; s += 256) g[s] = make_uint4(0u, 0u, 0u, 0u);

  float tiv[4], tjv[4];
#pragma unroll
  for (int a = 0; a < 4; ++a) {
    tiv[a] = (float)(-1.0 + 2.0 * (double)(i0 + ty + 16 * a) / (double)(WD - 1));
    tjv[a] = (float)(-1.0 + 2.0 * (double)(j0 + tx + 16 * a) / (double)(WD - 1));
  }
  const float hw = 0.5f * (float)(WD - 1);
  float acc[4][4][4] = {};   // [di][dj][img]

  // Staging: thread t builds slots GOFF+t (pair r=t) and GOFF+256+t (pair r=256+t).
  // Loads: per image floats at t, t+1, 256+t, 257+t (t+1 overlap served by L1).
  const bool lastt = (t == 255);
  const int a3idx = lastt ? 511 : (257 + t);
  float xr[4][4];
  {
    int lc = iA[0];
#pragma unroll
    for (int k = 0; k < 4; ++k) {
      const float* p = xf + ((size_t)(n0 + k) * WD + lc) * WD;
      xr[k][0] = p[t]; xr[k][1] = p[t + 1];
      xr[k][2] = p[256 + t]; xr[k][3] = p[a3idx];
    }
  }

  for (int l = 0; l < L; ++l) {
    float wAl = wA[l];
    float wBl = wB[l];
    float c = cs[l] * hw;
    float s = sn[l] * hw;

    float y[4][4];
#pragma unroll
    for (int k = 0; k < 4; ++k)
#pragma unroll
      for (int q = 0; q < 4; ++q) y[k][q] = xr[k][q];

    if (wBl != 0.f) {                 // generic angle interp (never taken, L==WD)
      int lc2 = iB[l];
#pragma unroll
      for (int k = 0; k < 4; ++k) {
        const float* p2 = xf + ((size_t)(n0 + k) * WD + lc2) * WD;
        y[k][0] = fmaf(y[k][0], wAl, p2[t] * wBl);
        y[k][1] = fmaf(y[k][1], wAl, p2[t + 1] * wBl);
        y[k][2] = fmaf(y[k][2], wAl, p2[256 + t] * wBl);
        y[k][3] = fmaf(y[k][3], wAl, p2[a3idx] * wBl);
      }
    } else if (wAl != 1.f) {
#pragma unroll
      for (int k = 0; k < 4; ++k)
#pragma unroll
        for (int q = 0; q < 4; ++q) y[k][q] *= wAl;
    }

    uint4 qa, qb;
    {
      float z0 = lastt ? 0.f : y[0][3];
      float z1 = lastt ? 0.f : y[1][3];
      float z2 = lastt ? 0.f : y[2][3];
      float z3 = lastt ? 0.f : y[3][3];
      qa.x = pkbits(y[0][0], y[0][1]); qa.y = pkbits(y[1][0], y[1][1]);
      qa.z = pkbits(y[2][0], y[2][1]); qa.w = pkbits(y[3][0], y[3][1]);
      qb.x = pkbits(y[0][2], z0);      qb.y = pkbits(y[1][2], z1);
      qb.z = pkbits(y[2][2], z2);      qb.w = pkbits(y[3][2], z3);
    }

    __syncthreads();                  // previous iteration's reads done
    g[GOFF + t] = qa;                 // stride-16B b128 writes: conflict-free
    g[GOFF + 256 + t] = qb;

    if (l + 1 < L) {                  // prefetch next angle during compute
      int lc = iA[l + 1];
#pragma unroll
      for (int k = 0; k < 4; ++k) {
        const float* p = xf + ((size_t)(n0 + k) * WD + lc) * WD;
        xr[k][0] = p[t]; xr[k][1] = p[t + 1];
        xr[k][2] = p[256 + t]; xr[k][3] = p[a3idx];
      }
    }
    __syncthreads();

#pragma unroll
    for (int di = 0; di < 4; ++di) {
      float bi = fmaf(tiv[di], -s, hw);
#pragma unroll
      for (int dj = 0; dj < 4; ++dj) {
        float ry = fmaf(tjv[dj], c, bi);
        int idx = (int)ry;            // trunc == floor inside circle (ry >= 0)
        float w1 = ry - (float)idx;
        half2_t wpk = pkh(1.f - w1, w1);
        uint4 q = g[idx + GOFF];      // single ds_read_b128, guards absorb OOB
        acc[di][dj][0] = dot2f(q.x, wpk, acc[di][dj][0]);
        acc[di][dj][1] = dot2f(q.y, wpk, acc[di][dj][1]);
        acc[di][dj][2] = dot2f(q.z, wpk, acc[di][dj][2]);
        acc[di][dj][3] = dot2f(q.w, wpk, acc[di][dj][3]);
      }
    }
  }

  const float scale = (float)(3.14159265358979323846 / (2.0 * (double)L));
#pragma unroll
  for (int k = 0; k < 4; ++k) {
    float* ob = out + (size_t)(n0 + k) * WD * WD;
#pragma unroll
    for (int di = 0; di < 4; ++di) {
      int ii = i0 + ty + 16 * di;
#pragma unroll
      for (int dj = 0; dj < 4; ++dj) {
        int jj = j0 + tx + 16 * dj;
        float rr = tiv[di] * tiv[di] + tjv[dj] * tjv[dj];
        ob[(size_t)ii * WD + jj] = (rr <= 1.f) ? acc[di][dj][k] * scale : 0.f;
      }
    }
  }
}

extern "C" void kernel_launch(void* const* d_in, const int* in_sizes, int n_in,
                              void* d_out, int out_size, void* d_ws, size_t ws_size,
                              hipStream_t stream) {
  const float* x = (const float*)d_in[0];
  const float* theta = (const float*)d_in[1];
  float* out = (float*)d_out;
  float* ws = (float*)d_ws;
  int L = in_sizes[1];                       // 512
  int NC = in_sizes[0] / (WD * WD);          // 32
  float* xf_t = ws + OFF_XF;

  int nset = LH2 + L;
  hipLaunchKernelGGL(setup_kernel, dim3((nset + 255) / 256), dim3(256), 0, stream,
                     theta, ws, L);
  hipLaunchKernelGGL(filter_kernel, dim3((WD / 64) * 8, NC), dim3(256), 0, stream,
                     x, ws, xf_t);
  hipLaunchKernelGGL(backproj_kernel, dim3(64, NC / 4), dim3(256), 0, stream,
                     ws, out, L);
}

// Round 4
// 797.335 us; speedup vs baseline: 2.0984x; 1.1822x over previous
//
#include <hip/hip_runtime.h>
#include <math.h>

// Problem constants (setup_inputs: N=32, C=1, W=512, L=512)
#define WD 512          // image / detector width
#define PF 1024         // FFT pad length
#define LH2 1028        // shifted ramp-kernel table length
#define HSW 1160        // swizzled h2 LDS size (max hsw(1023)=1150)

// Workspace layout (float offsets). ws bytes needed: 16384 + NG*512*512*16 = ~33.57MB
#define OFF_H2 0        // 1028 floats
#define OFF_ANG 2048    // 512 x float4 (chw, shw, wB, iA-bits)
#define OFF_PK 4096     // packed fp16 sinogram table: [g][l][s] uint4 (4 images x (y[s],y[s+1]))

#define GOFF 107        // LDS slot = detector_index + GOFF (guards absorb out-of-circle idx)
#define GSLOTS 726      // covers idx in [-107, 618]

typedef __fp16 half2_t __attribute__((ext_vector_type(2)));

__device__ __forceinline__ half2_t pkh(float a, float b) {
  return __builtin_amdgcn_cvt_pkrtz(a, b);   // v_cvt_pkrtz_f16_f32
}
__device__ __forceinline__ unsigned pkbits(float a, float b) {
  return __builtin_bit_cast(unsigned, pkh(a, b));
}
__device__ __forceinline__ float dot2f(unsigned tapbits, half2_t w, float c) {
  half2_t tp = __builtin_bit_cast(half2_t, tapbits);
  return __builtin_amdgcn_fdot2(tp, w, c, false);   // v_dot2_f32_f16
}
// Bank swizzle for stride-8-float access patterns: lanes at c+8t map to banks (c'+9t)%32,
// all 16 distinct -> conflict-free.
__device__ __forceinline__ int hsw(int i) { return i + (i >> 3); }

// ---------------------------------------------------------------------------
// Setup: ramp kernel h2[i] = h[(i-512) & 1023]; per-angle meta float4.
// ---------------------------------------------------------------------------
__global__ void setup_kernel(const float* __restrict__ theta,
                             float* __restrict__ ws, int L) {
  int gid = blockIdx.x * blockDim.x + threadIdx.x;
  if (gid < LH2) {
    int dd = gid - (PF / 2);
    if (dd < 0) dd = -dd;
    float acc = 0.f;
    for (int k = 0; k < PF; ++k) {
      int kk = (k <= PF / 2) ? k : (PF - k);
      float filt = 2.f * (float)kk * (1.f / (float)PF);
      int m = (k * dd) & (PF - 1);
      float arg = (float)m * (6.28318530717958647692f / (float)PF);
      acc = fmaf(filt, cosf(arg), acc);
    }
    ws[OFF_H2 + gid] = acc * (1.f / (float)PF);
  } else if (gid < LH2 + L) {
    int l = gid - LH2;
    double rad = (double)theta[l] * 0.017453292519943295;
    const float hw = 0.5f * (float)(WD - 1);
    float cx = (float)l * (float)((double)(WD - 1) / (double)(L - 1));
    float c0 = floorf(cx);
    float wc = cx - c0;
    int ia = (int)c0;
    float ok = (ia + 1 <= WD - 1) ? 1.f : 0.f;
    float4 a;
    a.x = (float)cos(rad) * hw;
    a.y = (float)sin(rad) * hw;
    a.z = wc * ok;                       // wB (0 when L==WD: identity mapping)
    a.w = __int_as_float(ia);
    ((float4*)(ws + OFF_ANG))[l] = a;
  }
}

// ---------------------------------------------------------------------------
// Ramp filter (circular convolution) writing the PACKED fp16 table directly:
//   pk[g][l][s].img_k = (fp16 y[s], fp16 y[s+1]),  y[r] = sum_m x[n][m][l]*h2[r-m+512]
// Tile: 64 l x 128 r per block, 4x8 microtile; image n = 4g+k owns byte lane k.
// Seam stitching: interior s full-dword; edge halves via short stores; s=511 hi=0.
// ---------------------------------------------------------------------------
__global__ __launch_bounds__(256) void filter_kernel(
    const float* __restrict__ x, const float* __restrict__ ws,
    unsigned char* __restrict__ pk) {
  __shared__ float h2l[HSW];
  __shared__ __align__(16) float bxl[64][68];
  const int t = threadIdx.x;
  const int tx = t & 15, ty = t >> 4;
  const int n = blockIdx.y;
  const int g = n >> 2, k = n & 3;
  const int rt = blockIdx.x & 3, lt = blockIdx.x >> 2;
  const int l0 = lt << 6, r0 = rt << 7;

  for (int i = t; i < LH2; i += 256) h2l[hsw(i)] = ws[OFF_H2 + i];

  float acc[4][8] = {};
  const float* __restrict__ xn = x + (size_t)n * WD * WD;

  for (int mc = 0; mc < WD; mc += 64) {
    __syncthreads();
#pragma unroll
    for (int q = 0; q < 4; ++q) {            // stage x[mc..mc+63][l0..l0+63]
      int fid = t + (q << 8);
      int row = fid >> 4;
      int c4 = (fid & 15) << 2;
      float4 v = *(const float4*)(xn + (size_t)(mc + row) * WD + l0 + c4);
      *(float4*)(&bxl[row][c4]) = v;
    }
    __syncthreads();
    const int rbase = r0 + (tx << 3) + 512 - mc;
    float w[8];
#pragma unroll
    for (int j = 0; j < 8; ++j) w[j] = h2l[hsw(rbase + j)];
#pragma unroll 8
    for (int m = 0; m < 64; ++m) {
      float4 bv = *(const float4*)(&bxl[m][ty << 2]);
      float nh = h2l[hsw(rbase - m - 1)];    // next window's low element
      float b[4] = {bv.x, bv.y, bv.z, bv.w};
#pragma unroll
      for (int li = 0; li < 4; ++li)
#pragma unroll
        for (int rj = 0; rj < 8; ++rj)
          acc[li][rj] = fmaf(b[li], w[rj], acc[li][rj]);
      w[7] = w[6]; w[6] = w[5]; w[5] = w[4]; w[4] = w[3];
      w[3] = w[2]; w[2] = w[1]; w[1] = w[0]; w[0] = nh;   // unroll-renamed
    }
  }

  // Epilogue: scatter into interleaved pk table (byte lane k of each 16B slot).
  const int first = r0 + (tx << 3);
#pragma unroll
  for (int li = 0; li < 4; ++li) {
    int l = l0 + (ty << 2) + li;
    size_t rowb = ((size_t)(g * 512 + l) * 512) * 16 + (size_t)(k << 2);
#pragma unroll
    for (int j = 0; j < 7; ++j) {            // full entries s = first .. first+6
      unsigned d = pkbits(acc[li][j], acc[li][j + 1]);
      *(unsigned*)(pk + rowb + (size_t)(first + j) * 16) = d;
    }
    unsigned lastp = pkbits(acc[li][7], 0.f);    // lo = y[first+7], hi = 0
    if (first + 7 == 511) {
      *(unsigned*)(pk + rowb + (size_t)511 * 16) = lastp;     // hi half must be 0
    } else {
      *(unsigned short*)(pk + rowb + (size_t)(first + 7) * 16) = (unsigned short)lastp;
    }
    if (first > 0) {                          // hi half of entry s = first-1
      unsigned fh = pkbits(acc[li][0], 0.f);
      *(unsigned short*)(pk + rowb + (size_t)(first - 1) * 16 + 2) = (unsigned short)fh;
    }
  }
}

// ---------------------------------------------------------------------------
// Backprojection v3: pre-packed rows + double-buffered LDS (1 barrier/angle)
// + one-angle-ahead software pipeline. Staging = 2 uint4 loads + 2 ds_write_b128.
// ---------------------------------------------------------------------------
__device__ __forceinline__ uint4 blend4(uint4 a, uint4 b, float wA, float wB) {
  unsigned r[4];
  const unsigned* pa = &a.x; const unsigned* pb = &b.x;
#pragma unroll
  for (int i = 0; i < 4; ++i) {
    half2_t ha = __builtin_bit_cast(half2_t, pa[i]);
    half2_t hb = __builtin_bit_cast(half2_t, pb[i]);
    r[i] = pkbits(fmaf((float)ha.x, wA, (float)hb.x * wB),
                  fmaf((float)ha.y, wA, (float)hb.y * wB));
  }
  return make_uint4(r[0], r[1], r[2], r[3]);
}

__device__ __forceinline__ void loadrow(const unsigned char* gb, float4 a, int t,
                                        uint4& v0, uint4& v1) {
  int ia = __float_as_int(a.w);
  const unsigned char* rb = gb + (size_t)ia * (512 * 16);
  v0 = *(const uint4*)(rb + (size_t)t * 16);
  v1 = *(const uint4*)(rb + (size_t)(256 + t) * 16);
  float wB = a.z;
  if (wB != 0.f) {                       // generic angle interp (never taken, L==WD)
    int ib = ia + 1 < 511 ? ia + 1 : 511;
    const unsigned char* rb2 = gb + (size_t)ib * (512 * 16);
    uint4 u0 = *(const uint4*)(rb2 + (size_t)t * 16);
    uint4 u1 = *(const uint4*)(rb2 + (size_t)(256 + t) * 16);
    float wA = 1.f - wB;
    v0 = blend4(v0, u0, wA, wB);
    v1 = blend4(v1, u1, wA, wB);
  }
}

__global__ __launch_bounds__(256) void backproj_kernel(
    const float* __restrict__ ws, const unsigned char* __restrict__ pk,
    float* __restrict__ out, int L) {
  __shared__ __align__(16) uint4 buf[2][GSLOTS];
  const int t = threadIdx.x;
  const int tx = t & 15, ty = t >> 4;
  const int j0 = (blockIdx.x & 7) << 6;
  const int i0 = (blockIdx.x >> 3) << 6;
  const int g = blockIdx.y;
  const int n0 = g << 2;

  const float4* __restrict__ angp = (const float4*)(ws + OFF_ANG);
  const unsigned char* gb = pk + (size_t)g * (512 * 512 * 16);

  for (int s = t; s < GSLOTS; s += 256) {
    buf[0][s] = make_uint4(0u, 0u, 0u, 0u);
    buf[1][s] = make_uint4(0u, 0u, 0u, 0u);
  }
  __syncthreads();

  float tiv[4], tjv[4];
#pragma unroll
  for (int a = 0; a < 4; ++a) {
    tiv[a] = (float)(-1.0 + 2.0 * (double)(i0 + ty + 16 * a) / (double)(WD - 1));
    tjv[a] = (float)(-1.0 + 2.0 * (double)(j0 + tx + 16 * a) / (double)(WD - 1));
  }
  const float hw = 0.5f * (float)(WD - 1);
  float acc[4][4][4] = {};   // [di][dj][img]

  float4 aC = angp[0];
  float4 aN = angp[L > 1 ? 1 : 0];
  uint4 v0, v1;
  loadrow(gb, aC, t, v0, v1);

  for (int l = 0; l < L; ++l) {
    uint4* bw = buf[l & 1];
    bw[GOFF + t] = v0;                 // ds_write_b128 x2, conflict-free
    bw[GOFF + 256 + t] = v1;
    float4 aF = angp[(l + 2 < L) ? (l + 2) : (L - 1)];
    if (l + 1 < L) loadrow(gb, aN, t, v0, v1);   // in flight during compute
    __syncthreads();                   // single barrier per angle (dbuf)

    const float chw = aC.x, shw = aC.y;
    const uint4* br = buf[l & 1];
#pragma unroll
    for (int di = 0; di < 4; ++di) {
      float bi = fmaf(tiv[di], -shw, hw);
#pragma unroll
      for (int dj = 0; dj < 4; ++dj) {
        float ry = fmaf(tjv[dj], chw, bi);
        int idx = (int)ry;             // trunc; OOB lands in zero guards, masked later
        float w1 = ry - (float)idx;
        half2_t wpk = pkh(1.f - w1, w1);
        uint4 q = br[idx + GOFF];      // single ds_read_b128 serves 4 images
        acc[di][dj][0] = dot2f(q.x, wpk, acc[di][dj][0]);
        acc[di][dj][1] = dot2f(q.y, wpk, acc[di][dj][1]);
        acc[di][dj][2] = dot2f(q.z, wpk, acc[di][dj][2]);
        acc[di][dj][3] = dot2f(q.w, wpk, acc[di][dj][3]);
      }
    }
    aC = aN; aN = aF;
  }

  const float scale = (float)(3.14159265358979323846 / (2.0 * (double)L));
#pragma unroll
  for (int k = 0; k < 4; ++k) {
    float* ob = out + (size_t)(n0 + k) * WD * WD;
#pragma unroll
    for (int di = 0; di < 4; ++di) {
      int ii = i0 + ty + 16 * di;
#pragma unroll
      for (int dj = 0; dj < 4; ++dj) {
        int jj = j0 + tx + 16 * dj;
        float rr = tiv[di] * tiv[di] + tjv[dj] * tjv[dj];
        ob[(size_t)ii * WD + jj] = (rr <= 1.f) ? acc[di][dj][k] * scale : 0.f;
      }
    }
  }
}

extern "C" void kernel_launch(void* const* d_in, const int* in_sizes, int n_in,
                              void* d_out, int out_size, void* d_ws, size_t ws_size,
                              hipStream_t stream) {
  const float* x = (const float*)d_in[0];
  const float* theta = (const float*)d_in[1];
  float* out = (float*)d_out;
  float* ws = (float*)d_ws;
  int L = in_sizes[1];                       // 512
  int NC = in_sizes[0] / (WD * WD);          // 32
  int NG = NC >> 2;                          // 8 groups of 4 images
  unsigned char* pk = (unsigned char*)(ws + OFF_PK);

  int nset = LH2 + L;
  hipLaunchKernelGGL(setup_kernel, dim3((nset + 255) / 256), dim3(256), 0, stream,
                     theta, ws, L);
  hipLaunchKernelGGL(filter_kernel, dim3(32, NC), dim3(256), 0, stream,
                     x, ws, pk);
  hipLaunchKernelGGL(backproj_kernel, dim3(64, NG), dim3(256), 0, stream,
                     ws, pk, out, L);
}

// Round 5
// 675.314 us; speedup vs baseline: 2.4776x; 1.1807x over previous
//
#include <hip/hip_runtime.h>
#include <math.h>

// Problem constants (setup_inputs: N=32, C=1, W=512, L=512)
#define WD 512          // image / detector width
#define PF 1024         // FFT pad length
#define LH2 1028        // shifted ramp-kernel table length
#define HSW 1160        // swizzled h2 LDS size (max hsw(1023+128) < 1160)

// Workspace layout (float offsets). ws bytes: 16 KB + 33.55 MB table.
#define OFF_H2 0        // 1028 floats
#define OFF_ANG 2048    // 512 x float4 (chw, shw, wB, iA-bits)
#define OFF_PK 4096     // packed fp16 sinogram: [half][g4][l][s] uint4 (4 imgs x (y[s],y[s+1]))

#define GOFF 107        // LDS slot = detector_index + GOFF (guards absorb out-of-circle idx)
#define GSLOTS 726      // covers idx in [-107, 618]

typedef __fp16 half2_t __attribute__((ext_vector_type(2)));

__device__ __forceinline__ half2_t pkh(float a, float b) {
  return __builtin_amdgcn_cvt_pkrtz(a, b);   // v_cvt_pkrtz_f16_f32
}
__device__ __forceinline__ unsigned pkbits(float a, float b) {
  return __builtin_bit_cast(unsigned, pkh(a, b));
}
__device__ __forceinline__ float dot2f(unsigned tapbits, half2_t w, float c) {
  half2_t tp = __builtin_bit_cast(half2_t, tapbits);
  return __builtin_amdgcn_fdot2(tp, w, c, false);   // v_dot2_f32_f16
}
// Bank swizzle for stride-16-float lanes: 16t -> 18t mod 32, all 16 distinct.
__device__ __forceinline__ int hsw(int i) { return i + (i >> 3); }

// ---------------------------------------------------------------------------
// Setup: h2[i] = h[(i-512) & 1023] via v_cos (arg in REVOLUTIONS: cos(2pi*f)).
// ---------------------------------------------------------------------------
__global__ void setup_kernel(const float* __restrict__ theta,
                             float* __restrict__ ws, int L) {
  int gid = blockIdx.x * blockDim.x + threadIdx.x;
  if (gid < LH2) {
    int dd = gid - (PF / 2);
    if (dd < 0) dd = -dd;
    float acc = 0.f;
    for (int k = 0; k < PF; ++k) {
      int kk = (k <= PF / 2) ? k : (PF - k);
      float filt = 2.f * (float)kk * (1.f / (float)PF);
      int m = (k * dd) & (PF - 1);            // phase in [0,1) revolutions
#if __has_builtin(__builtin_amdgcn_cosf)
      float cv = __builtin_amdgcn_cosf((float)m * (1.f / (float)PF));
#else
      float cv = cosf((float)m * (6.28318530717958647692f / (float)PF));
#endif
      acc = fmaf(filt, cv, acc);
    }
    ws[OFF_H2 + gid] = acc * (1.f / (float)PF);
  } else if (gid < LH2 + L) {
    int l = gid - LH2;
    double rad = (double)theta[l] * 0.017453292519943295;
    const float hw = 0.5f * (float)(WD - 1);
    float cx = (float)l * (float)((double)(WD - 1) / (double)(L - 1));
    float c0 = floorf(cx);
    float wc = cx - c0;
    int ia = (int)c0;
    float ok = (ia + 1 <= WD - 1) ? 1.f : 0.f;
    float4 a;
    a.x = (float)cos(rad) * hw;
    a.y = (float)sin(rad) * hw;
    a.z = wc * ok;                       // wB (0 when L==WD)
    a.w = __int_as_float(ia);
    ((float4*)(ws + OFF_ANG))[l] = a;
  }
}

// ---------------------------------------------------------------------------
// Ramp filter -> packed fp16 table. Tile: 64 l x 256 r, 4x16 microtile.
// Image n owns byte lane (n&3) of half (n>>2)&1, group n>>3.
// ---------------------------------------------------------------------------
__global__ __launch_bounds__(256) void filter_kernel(
    const float* __restrict__ x, const float* __restrict__ ws,
    unsigned char* __restrict__ pk) {
  __shared__ float h2l[HSW];
  __shared__ __align__(16) float bxl[64][68];
  const int t = threadIdx.x;
  const int tx = t & 15, ty = t >> 4;
  const int n = blockIdx.y;
  const int g4 = n >> 3, hf = (n >> 2) & 1, k = n & 3;
  const int rt = blockIdx.x & 1, lt = blockIdx.x >> 1;
  const int l0 = lt << 6, r0 = rt << 8;

  for (int i = t; i < LH2; i += 256) h2l[hsw(i)] = ws[OFF_H2 + i];

  float acc[4][16] = {};
  const float* __restrict__ xn = x + (size_t)n * WD * WD;
  const int first = r0 + (tx << 4);

  for (int mc = 0; mc < WD; mc += 64) {
    __syncthreads();
#pragma unroll
    for (int q = 0; q < 4; ++q) {            // stage x[mc..mc+63][l0..l0+63]
      int fid = t + (q << 8);
      int row = fid >> 4;
      int c4 = (fid & 15) << 2;
      float4 v = *(const float4*)(xn + (size_t)(mc + row) * WD + l0 + c4);
      *(float4*)(&bxl[row][c4]) = v;
    }
    __syncthreads();
    const int rbase = first + 512 - mc;
    float w[16];
#pragma unroll
    for (int j = 0; j < 16; ++j) w[j] = h2l[hsw(rbase + j)];
#pragma unroll 16
    for (int m = 0; m < 64; ++m) {
      float4 bv = *(const float4*)(&bxl[m][ty << 2]);
      float nh = h2l[hsw(rbase - m - 1)];
      float b[4] = {bv.x, bv.y, bv.z, bv.w};
#pragma unroll
      for (int li = 0; li < 4; ++li)
#pragma unroll
        for (int rj = 0; rj < 16; ++rj)
          acc[li][rj] = fmaf(b[li], w[rj], acc[li][rj]);
#pragma unroll
      for (int j = 15; j > 0; --j) w[j] = w[j - 1];   // renamed by unroll-16
      w[0] = nh;
    }
  }

  // Epilogue: scatter into interleaved pk table (byte lane k, half hf, group g4).
#pragma unroll
  for (int li = 0; li < 4; ++li) {
    int l = l0 + (ty << 2) + li;
    size_t rowb = ((size_t)((hf * 4 + g4) * 512 + l) * 512) * 16 + (size_t)(k << 2);
#pragma unroll
    for (int j = 0; j < 15; ++j) {           // full entries s = first .. first+14
      unsigned d = pkbits(acc[li][j], acc[li][j + 1]);
      *(unsigned*)(pk + rowb + (size_t)(first + j) * 16) = d;
    }
    unsigned lastp = pkbits(acc[li][15], 0.f);
    if (first + 15 == 511) {
      *(unsigned*)(pk + rowb + (size_t)511 * 16) = lastp;     // hi half must be 0
    } else {
      *(unsigned short*)(pk + rowb + (size_t)(first + 15) * 16) = (unsigned short)lastp;
    }
    if (first > 0) {                          // hi half of entry s = first-1
      unsigned fh = pkbits(acc[li][0], 0.f);
      *(unsigned short*)(pk + rowb + (size_t)(first - 1) * 16 + 2) = (unsigned short)fh;
    }
  }
}

// ---------------------------------------------------------------------------
// Backprojection v4: 8 images per block (two 16B-stride LDS half-regions),
// 64(i) x 32(j) pixel tile, double-buffered, one barrier per angle.
// Per pixel: ~6 VALU + 2 ds_read_b128 + 8 v_dot2 serving 8 images.
// ---------------------------------------------------------------------------
__device__ __forceinline__ uint4 blend4(uint4 a, uint4 b, float wA, float wB) {
  unsigned r[4];
  const unsigned* pa = &a.x; const unsigned* pb = &b.x;
#pragma unroll
  for (int i = 0; i < 4; ++i) {
    half2_t ha = __builtin_bit_cast(half2_t, pa[i]);
    half2_t hb = __builtin_bit_cast(half2_t, pb[i]);
    r[i] = pkbits(fmaf((float)ha.x, wA, (float)hb.x * wB),
                  fmaf((float)ha.y, wA, (float)hb.y * wB));
  }
  return make_uint4(r[0], r[1], r[2], r[3]);
}

__device__ __forceinline__ void loadrow8(const unsigned char* gb0,
                                         const unsigned char* gb1,
                                         float4 a, int t, uint4 v[4]) {
  int ia = __float_as_int(a.w);
  const unsigned char* r0 = gb0 + (size_t)ia * (512 * 16);
  const unsigned char* r1 = gb1 + (size_t)ia * (512 * 16);
  v[0] = *(const uint4*)(r0 + (size_t)t * 16);
  v[1] = *(const uint4*)(r0 + (size_t)(256 + t) * 16);
  v[2] = *(const uint4*)(r1 + (size_t)t * 16);
  v[3] = *(const uint4*)(r1 + (size_t)(256 + t) * 16);
  float wB = a.z;
  if (wB != 0.f) {                       // generic angle interp (never taken, L==WD)
    int ib = ia + 1 < 511 ? ia + 1 : 511;
    const unsigned char* q0 = gb0 + (size_t)ib * (512 * 16);
    const unsigned char* q1 = gb1 + (size_t)ib * (512 * 16);
    float wA = 1.f - wB;
    v[0] = blend4(v[0], *(const uint4*)(q0 + (size_t)t * 16), wA, wB);
    v[1] = blend4(v[1], *(const uint4*)(q0 + (size_t)(256 + t) * 16), wA, wB);
    v[2] = blend4(v[2], *(const uint4*)(q1 + (size_t)t * 16), wA, wB);
    v[3] = blend4(v[3], *(const uint4*)(q1 + (size_t)(256 + t) * 16), wA, wB);
  }
}

__global__ __launch_bounds__(256) void backproj_kernel(
    const float* __restrict__ ws, const unsigned char* __restrict__ pk,
    float* __restrict__ out, int L) {
  __shared__ __align__(16) uint4 buf[2][2][GSLOTS];   // [dbuf][half][slot]
  const int t = threadIdx.x;
  const int tx = t & 15, ty = t >> 4;
  const int j0 = (blockIdx.x & 15) << 5;
  const int i0 = (blockIdx.x >> 4) << 6;
  const int g4 = blockIdx.y;
  const int n0 = g4 << 3;

  const float4* __restrict__ angp = (const float4*)(ws + OFF_ANG);
  const unsigned char* gb0 = pk + (size_t)(g4) * (512 * 512 * 16);
  const unsigned char* gb1 = pk + (size_t)(4 + g4) * (512 * 512 * 16);

  for (int s = t; s < 2 * 2 * GSLOTS; s += 256)
    ((uint4*)buf)[s] = make_uint4(0u, 0u, 0u, 0u);
  __syncthreads();                       // guards visible before first compute

  float tiv[4], tjv[2];
#pragma unroll
  for (int a = 0; a < 4; ++a)
    tiv[a] = (float)(-1.0 + 2.0 * (double)(i0 + ty + 16 * a) / (double)(WD - 1));
#pragma unroll
  for (int a = 0; a < 2; ++a)
    tjv[a] = (float)(-1.0 + 2.0 * (double)(j0 + tx + 16 * a) / (double)(WD - 1));

  const float hw = 0.5f * (float)(WD - 1);
  float acc[4][2][8] = {};   // [di][dj][img]

  float4 aC = angp[0];
  float4 aN = angp[L > 1 ? 1 : 0];
  uint4 v[4];
  loadrow8(gb0, gb1, aC, t, v);

  for (int l = 0; l < L; ++l) {
    uint4* bA = &buf[l & 1][0][0];
    uint4* bB = &buf[l & 1][1][0];
    bA[GOFF + t] = v[0];                 // all stride-16B b128: conflict-free
    bA[GOFF + 256 + t] = v[1];
    bB[GOFF + t] = v[2];
    bB[GOFF + 256 + t] = v[3];
    float4 aF = angp[(l + 2 < L) ? (l + 2) : (L - 1)];
    if (l + 1 < L) loadrow8(gb0, gb1, aN, t, v);   // in flight during compute
    __syncthreads();                     // single barrier per angle (dbuf)

    const float chw = aC.x, shw = aC.y;
    const uint4* brA = &buf[l & 1][0][0];
    const uint4* brB = &buf[l & 1][1][0];
#pragma unroll
    for (int di = 0; di < 4; ++di) {
      float bi = fmaf(tiv[di], -shw, hw);
#pragma unroll
      for (int dj = 0; dj < 2; ++dj) {
        float ry = fmaf(tjv[dj], chw, bi);
        int idx = (int)ry;               // trunc; OOB lands in zero guards
        float w1 = ry - (float)idx;
        half2_t wpk = pkh(1.f - w1, w1);
        uint4 qa = brA[idx + GOFF];      // imgs 0-3
        uint4 qb = brB[idx + GOFF];      // imgs 4-7
        acc[di][dj][0] = dot2f(qa.x, wpk, acc[di][dj][0]);
        acc[di][dj][1] = dot2f(qa.y, wpk, acc[di][dj][1]);
        acc[di][dj][2] = dot2f(qa.z, wpk, acc[di][dj][2]);
        acc[di][dj][3] = dot2f(qa.w, wpk, acc[di][dj][3]);
        acc[di][dj][4] = dot2f(qb.x, wpk, acc[di][dj][4]);
        acc[di][dj][5] = dot2f(qb.y, wpk, acc[di][dj][5]);
        acc[di][dj][6] = dot2f(qb.z, wpk, acc[di][dj][6]);
        acc[di][dj][7] = dot2f(qb.w, wpk, acc[di][dj][7]);
      }
    }
    aC = aN; aN = aF;
  }

  const float scale = (float)(3.14159265358979323846 / (2.0 * (double)L));
#pragma unroll
  for (int k = 0; k < 8; ++k) {
    float* ob = out + (size_t)(n0 + k) * WD * WD;
#pragma unroll
    for (int di = 0; di < 4; ++di) {
      int ii = i0 + ty + 16 * di;
#pragma unroll
      for (int dj = 0; dj < 2; ++dj) {
        int jj = j0 + tx + 16 * dj;
        float rr = tiv[di] * tiv[di] + tjv[dj] * tjv[dj];
        ob[(size_t)ii * WD + jj] = (rr <= 1.f) ? acc[di][dj][k] * scale : 0.f;
      }
    }
  }
}

extern "C" void kernel_launch(void* const* d_in, const int* in_sizes, int n_in,
                              void* d_out, int out_size, void* d_ws, size_t ws_size,
                              hipStream_t stream) {
  const float* x = (const float*)d_in[0];
  const float* theta = (const float*)d_in[1];
  float* out = (float*)d_out;
  float* ws = (float*)d_ws;
  int L = in_sizes[1];                       // 512
  int NC = in_sizes[0] / (WD * WD);          // 32
  unsigned char* pk = (unsigned char*)(ws + OFF_PK);

  int nset = LH2 + L;
  hipLaunchKernelGGL(setup_kernel, dim3((nset + 255) / 256), dim3(256), 0, stream,
                     theta, ws, L);
  hipLaunchKernelGGL(filter_kernel, dim3(16, NC), dim3(256), 0, stream,
                     x, ws, pk);
  hipLaunchKernelGGL(backproj_kernel, dim3(128, NC / 8), dim3(256), 0, stream,
                     ws, pk, out, L);
}

// Round 6
// 627.664 us; speedup vs baseline: 2.6657x; 1.0759x over previous
//
#include <hip/hip_runtime.h>
#include <math.h>

// Problem constants (setup_inputs: N=32, C=1, W=512, L=512)
#define WD 512          // image / detector width
#define PF 1024         // FFT pad length
#define LH2 1028        // shifted ramp-kernel table length
#define HSW 1160        // swizzled h2 LDS size (max hsw(1023)=1150)

// Workspace layout (float offsets). ws bytes: 16 KB + 33.55 MB table.
#define OFF_H2 0        // 1028 floats
#define OFF_ANG 2048    // 512 x float4 (chw, shw, wB, iA-bits)
#define OFF_PK 4096     // packed fp16 sinogram: [g][l][s] uint4 (4 imgs x (y[s],y[s+1]))

#define GOFF 107        // LDS slot = detector_index + GOFF (guards absorb out-of-circle idx)
#define GSLOTS 726      // covers idx in [-107, 618]

typedef __fp16 half2_t __attribute__((ext_vector_type(2)));

__device__ __forceinline__ half2_t pkh(float a, float b) {
  return __builtin_amdgcn_cvt_pkrtz(a, b);   // v_cvt_pkrtz_f16_f32
}
__device__ __forceinline__ unsigned pkbits(float a, float b) {
  return __builtin_bit_cast(unsigned, pkh(a, b));
}
__device__ __forceinline__ float dot2f(unsigned tapbits, half2_t w, float c) {
  half2_t tp = __builtin_bit_cast(half2_t, tapbits);
  return __builtin_amdgcn_fdot2(tp, w, c, false);   // v_dot2_f32_f16
}
// Bank swizzle for stride-16-float lanes: 16t -> 18t mod 32 (16 banks x2 = free).
__device__ __forceinline__ int hsw(int i) { return i + (i >> 3); }

// ---------------------------------------------------------------------------
// Setup: h2[i] = h[(i-512) & 1023] via v_cos (arg in REVOLUTIONS).
// ---------------------------------------------------------------------------
__global__ void setup_kernel(const float* __restrict__ theta,
                             float* __restrict__ ws, int L) {
  int gid = blockIdx.x * blockDim.x + threadIdx.x;
  if (gid < LH2) {
    int dd = gid - (PF / 2);
    if (dd < 0) dd = -dd;
    float acc = 0.f;
    for (int k = 0; k < PF; ++k) {
      int kk = (k <= PF / 2) ? k : (PF - k);
      float filt = 2.f * (float)kk * (1.f / (float)PF);
      int m = (k * dd) & (PF - 1);            // phase in [0,1) revolutions
#if __has_builtin(__builtin_amdgcn_cosf)
      float cv = __builtin_amdgcn_cosf((float)m * (1.f / (float)PF));
#else
      float cv = cosf((float)m * (6.28318530717958647692f / (float)PF));
#endif
      acc = fmaf(filt, cv, acc);
    }
    ws[OFF_H2 + gid] = acc * (1.f / (float)PF);
  } else if (gid < LH2 + L) {
    int l = gid - LH2;
    double rad = (double)theta[l] * 0.017453292519943295;
    const float hw = 0.5f * (float)(WD - 1);
    float cx = (float)l * (float)((double)(WD - 1) / (double)(L - 1));
    float c0 = floorf(cx);
    float wc = cx - c0;
    int ia = (int)c0;
    float ok = (ia + 1 <= WD - 1) ? 1.f : 0.f;
    float4 a;
    a.x = (float)cos(rad) * hw;
    a.y = (float)sin(rad) * hw;
    a.z = wc * ok;                       // wB (0 when L==WD)
    a.w = __int_as_float(ia);
    ((float4*)(ws + OFF_ANG))[l] = a;
  }
}

// ---------------------------------------------------------------------------
// Ramp filter -> packed fp16 table. 512-thread block: 64 l x FULL 512 r,
// 4x16 microtile; x staged ONCE. Image n -> table group n>>2, byte lane n&3.
// ---------------------------------------------------------------------------
__global__ __launch_bounds__(512) void filter_kernel(
    const float* __restrict__ x, const float* __restrict__ ws,
    unsigned char* __restrict__ pk) {
  __shared__ float h2l[HSW];
  __shared__ __align__(16) float bxl[64][68];
  const int t = threadIdx.x;
  const int tx = t & 31, ty = t >> 5;        // tx: r/16, ty: l/4
  const int n = blockIdx.y;
  const int g = n >> 2, k = n & 3;
  const int l0 = blockIdx.x << 6;

  for (int i = t; i < LH2; i += 512) h2l[hsw(i)] = ws[OFF_H2 + i];

  float acc[4][16] = {};
  const float* __restrict__ xn = x + (size_t)n * WD * WD;
  const int first = tx << 4;

  for (int mc = 0; mc < WD; mc += 64) {
    __syncthreads();
#pragma unroll
    for (int q = 0; q < 2; ++q) {            // stage x[mc..mc+63][l0..l0+63]
      int fid = t + (q << 9);
      int row = fid >> 4;
      int c4 = (fid & 15) << 2;
      float4 v = *(const float4*)(xn + (size_t)(mc + row) * WD + l0 + c4);
      *(float4*)(&bxl[row][c4]) = v;
    }
    __syncthreads();
    const int rbase = first + 512 - mc;
    float w[16];
#pragma unroll
    for (int j = 0; j < 16; ++j) w[j] = h2l[hsw(rbase + j)];
#pragma unroll 16
    for (int m = 0; m < 64; ++m) {
      float4 bv = *(const float4*)(&bxl[m][ty << 2]);
      float nh = h2l[hsw(rbase - m - 1)];
      float b[4] = {bv.x, bv.y, bv.z, bv.w};
#pragma unroll
      for (int li = 0; li < 4; ++li)
#pragma unroll
        for (int rj = 0; rj < 16; ++rj)
          acc[li][rj] = fmaf(b[li], w[rj], acc[li][rj]);
#pragma unroll
      for (int j = 15; j > 0; --j) w[j] = w[j - 1];   // renamed by unroll-16
      w[0] = nh;
    }
  }

  // Epilogue: scatter into interleaved pk table (byte lane k, group g).
#pragma unroll
  for (int li = 0; li < 4; ++li) {
    int l = l0 + (ty << 2) + li;
    size_t rowb = ((size_t)(g * 512 + l) * 512) * 16 + (size_t)(k << 2);
#pragma unroll
    for (int j = 0; j < 15; ++j) {           // full entries s = first .. first+14
      unsigned d = pkbits(acc[li][j], acc[li][j + 1]);
      *(unsigned*)(pk + rowb + (size_t)(first + j) * 16) = d;
    }
    unsigned lastp = pkbits(acc[li][15], 0.f);
    if (first + 15 == 511) {
      *(unsigned*)(pk + rowb + (size_t)511 * 16) = lastp;     // hi half must be 0
    } else {
      *(unsigned short*)(pk + rowb + (size_t)(first + 15) * 16) = (unsigned short)lastp;
    }
    if (first > 0) {                          // hi half of entry s = first-1
      unsigned fh = pkbits(acc[li][0], 0.f);
      *(unsigned short*)(pk + rowb + (size_t)(first - 1) * 16 + 2) = (unsigned short)fh;
    }
  }
}

// ---------------------------------------------------------------------------
// Backprojection v5: 512-thread blocks, 64x64 px tile x 4 imgs, dbuf LDS,
// 1 barrier/angle. Staging = 1 uint4 load + 1 ds_write_b128 per thread.
// 16 waves/CU (4/SIMD) hide the LDS read latency; LDS-BW-bound.
// ---------------------------------------------------------------------------
__device__ __forceinline__ uint4 blend4(uint4 a, uint4 b, float wA, float wB) {
  unsigned r[4];
  const unsigned* pa = &a.x; const unsigned* pb = &b.x;
#pragma unroll
  for (int i = 0; i < 4; ++i) {
    half2_t ha = __builtin_bit_cast(half2_t, pa[i]);
    half2_t hb = __builtin_bit_cast(half2_t, pb[i]);
    r[i] = pkbits(fmaf((float)ha.x, wA, (float)hb.x * wB),
                  fmaf((float)ha.y, wA, (float)hb.y * wB));
  }
  return make_uint4(r[0], r[1], r[2], r[3]);
}

__device__ __forceinline__ void loadrow(const unsigned char* gb, float4 a, int t,
                                        uint4& v) {
  int ia = __float_as_int(a.w);
  v = *(const uint4*)(gb + (size_t)ia * (512 * 16) + (size_t)t * 16);
  float wB = a.z;
  if (wB != 0.f) {                       // generic angle interp (never taken, L==WD)
    int ib = ia + 1 < 511 ? ia + 1 : 511;
    uint4 u = *(const uint4*)(gb + (size_t)ib * (512 * 16) + (size_t)t * 16);
    v = blend4(v, u, 1.f - wB, wB);
  }
}

__global__ __launch_bounds__(512) void backproj_kernel(
    const float* __restrict__ ws, const unsigned char* __restrict__ pk,
    float* __restrict__ out, int L) {
  __shared__ __align__(16) uint4 buf[2][GSLOTS];
  const int t = threadIdx.x;
  const int tx = t & 15, ty = t >> 4;        // ty: 0..31
  const int j0 = (blockIdx.x & 7) << 6;
  const int i0 = (blockIdx.x >> 3) << 6;
  const int g = blockIdx.y;
  const int n0 = g << 2;

  const float4* __restrict__ angp = (const float4*)(ws + OFF_ANG);
  const unsigned char* gb = pk + (size_t)g * (512 * 512 * 16);

  for (int s = t; s < 2 * GSLOTS; s += 512)
    ((uint4*)buf)[s] = make_uint4(0u, 0u, 0u, 0u);
  __syncthreads();                       // guards visible before first compute

  float tiv[2], tjv[4];
#pragma unroll
  for (int a = 0; a < 2; ++a)
    tiv[a] = (float)(-1.0 + 2.0 * (double)(i0 + ty + 32 * a) / (double)(WD - 1));
#pragma unroll
  for (int a = 0; a < 4; ++a)
    tjv[a] = (float)(-1.0 + 2.0 * (double)(j0 + tx + 16 * a) / (double)(WD - 1));

  const float hw = 0.5f * (float)(WD - 1);
  float acc[2][4][4] = {};   // [di][dj][img]

  float4 aC = angp[0];
  float4 aN = angp[L > 1 ? 1 : 0];
  uint4 v;
  loadrow(gb, aC, t, v);

  for (int l = 0; l < L; ++l) {
    buf[l & 1][GOFF + t] = v;            // 1 ds_write_b128/thread, conflict-free
    float4 aF = angp[(l + 2 < L) ? (l + 2) : (L - 1)];
    if (l + 1 < L) loadrow(gb, aN, t, v);   // in flight during compute
    __syncthreads();                     // single barrier per angle (dbuf)

    const float chw = aC.x, shw = aC.y;
    const uint4* br = &buf[l & 1][0];
#pragma unroll
    for (int di = 0; di < 2; ++di) {
      float bi = fmaf(tiv[di], -shw, hw);
#pragma unroll
      for (int dj = 0; dj < 4; ++dj) {
        float ry = fmaf(tjv[dj], chw, bi);
        int idx = (int)ry;               // trunc; OOB lands in zero guards
        float w1 = ry - (float)idx;
        half2_t wpk = pkh(1.f - w1, w1);
        uint4 q = br[idx + GOFF];        // one ds_read_b128 serves 4 images
        acc[di][dj][0] = dot2f(q.x, wpk, acc[di][dj][0]);
        acc[di][dj][1] = dot2f(q.y, wpk, acc[di][dj][1]);
        acc[di][dj][2] = dot2f(q.z, wpk, acc[di][dj][2]);
        acc[di][dj][3] = dot2f(q.w, wpk, acc[di][dj][3]);
      }
    }
    aC = aN; aN = aF;
  }

  const float scale = (float)(3.14159265358979323846 / (2.0 * (double)L));
#pragma unroll
  for (int k = 0; k < 4; ++k) {
    float* ob = out + (size_t)(n0 + k) * WD * WD;
#pragma unroll
    for (int di = 0; di < 2; ++di) {
      int ii = i0 + ty + 32 * di;
#pragma unroll
      for (int dj = 0; dj < 4; ++dj) {
        int jj = j0 + tx + 16 * dj;
        float rr = tiv[di] * tiv[di] + tjv[dj] * tjv[dj];
        ob[(size_t)ii * WD + jj] = (rr <= 1.f) ? acc[di][dj][k] * scale : 0.f;
      }
    }
  }
}

extern "C" void kernel_launch(void* const* d_in, const int* in_sizes, int n_in,
                              void* d_out, int out_size, void* d_ws, size_t ws_size,
                              hipStream_t stream) {
  const float* x = (const float*)d_in[0];
  const float* theta = (const float*)d_in[1];
  float* out = (float*)d_out;
  float* ws = (float*)d_ws;
  int L = in_sizes[1];                       // 512
  int NC = in_sizes[0] / (WD * WD);          // 32
  unsigned char* pk = (unsigned char*)(ws + OFF_PK);

  int nset = LH2 + L;
  hipLaunchKernelGGL(setup_kernel, dim3((nset + 255) / 256), dim3(256), 0, stream,
                     theta, ws, L);
  hipLaunchKernelGGL(filter_kernel, dim3(8, NC), dim3(512), 0, stream,
                     x, ws, pk);
  hipLaunchKernelGGL(backproj_kernel, dim3(64, NC / 4), dim3(512), 0, stream,
                     ws, pk, out, L);
}

// Round 7
// 593.482 us; speedup vs baseline: 2.8192x; 1.0576x over previous
//
#include <hip/hip_runtime.h>
#include <math.h>

// Problem constants (setup_inputs: N=32, C=1, W=512, L=512)
#define WD 512          // image / detector width
#define PF 1024         // FFT pad length
#define LH2 1028        // shifted ramp-kernel table length
#define HSW 1160        // swizzled h2 LDS size (max hsw(1023)=1150)

// Workspace layout (float offsets). ws bytes: 16 KB + 33.55 MB table.
#define OFF_H2 0        // 1028 floats
#define OFF_ANG 2048    // 512 x float4 (chw, shw, wB, iA-bits)
#define OFF_PK 4096     // packed fp16 sinogram: [g][l][s] uint4 (4 imgs x (y[s],y[s+1]))

#define GOFF 107        // LDS slot = detector_index + GOFF (guards absorb out-of-circle idx)
#define GSLOTS 726      // covers idx in [-107, 618]

typedef __fp16 half2_t __attribute__((ext_vector_type(2)));

__device__ __forceinline__ half2_t pkh(float a, float b) {
  return __builtin_amdgcn_cvt_pkrtz(a, b);   // v_cvt_pkrtz_f16_f32
}
__device__ __forceinline__ unsigned pkbits(float a, float b) {
  return __builtin_bit_cast(unsigned, pkh(a, b));
}
__device__ __forceinline__ float dot2f(unsigned tapbits, half2_t w, float c) {
  half2_t tp = __builtin_bit_cast(half2_t, tapbits);
  return __builtin_amdgcn_fdot2(tp, w, c, false);   // v_dot2_f32_f16
}
// Bank swizzle: stride-16-float lanes -> stride 18 mod 32 (2-way = free).
__device__ __forceinline__ int hsw(int i) { return i + (i >> 3); }

__device__ __forceinline__ float t2(int p) {
  return (float)(-1.0 + 2.0 * (double)p / (double)(WD - 1));
}

// ---------------------------------------------------------------------------
// Setup: h2[i] = h[(i-512) & 1023] via v_cos (arg in REVOLUTIONS).
// ---------------------------------------------------------------------------
__global__ void setup_kernel(const float* __restrict__ theta,
                             float* __restrict__ ws, int L) {
  int gid = blockIdx.x * blockDim.x + threadIdx.x;
  if (gid < LH2) {
    int dd = gid - (PF / 2);
    if (dd < 0) dd = -dd;
    float acc = 0.f;
    for (int k = 0; k < PF; ++k) {
      int kk = (k <= PF / 2) ? k : (PF - k);
      float filt = 2.f * (float)kk * (1.f / (float)PF);
      int m = (k * dd) & (PF - 1);            // phase in [0,1) revolutions
#if __has_builtin(__builtin_amdgcn_cosf)
      float cv = __builtin_amdgcn_cosf((float)m * (1.f / (float)PF));
#else
      float cv = cosf((float)m * (6.28318530717958647692f / (float)PF));
#endif
      acc = fmaf(filt, cv, acc);
    }
    ws[OFF_H2 + gid] = acc * (1.f / (float)PF);
  } else if (gid < LH2 + L) {
    int l = gid - LH2;
    double rad = (double)theta[l] * 0.017453292519943295;
    const float hw = 0.5f * (float)(WD - 1);
    float cx = (float)l * (float)((double)(WD - 1) / (double)(L - 1));
    float c0 = floorf(cx);
    float wc = cx - c0;
    int ia = (int)c0;
    float ok = (ia + 1 <= WD - 1) ? 1.f : 0.f;
    float4 a;
    a.x = (float)cos(rad) * hw;
    a.y = (float)sin(rad) * hw;
    a.z = wc * ok;                       // wB (0 when L==WD)
    a.w = __int_as_float(ia);
    ((float4*)(ws + OFF_ANG))[l] = a;
  }
}

// ---------------------------------------------------------------------------
// Ramp filter -> packed fp16 table. 256-thread block, tile 16 l x 512 r,
// 2x16 microtile, 4 blocks/CU (4 waves/SIMD). Loads batched per 8-m chunk
// so the rolling h-window never serializes on lgkmcnt.
// ---------------------------------------------------------------------------
__global__ __launch_bounds__(256, 4) void filter_kernel(
    const float* __restrict__ x, const float* __restrict__ ws,
    unsigned char* __restrict__ pk) {
  __shared__ float h2l[HSW];
  __shared__ __align__(16) float bxl[64][20];   // [m][l], 16 l + 4 pad
  const int t = threadIdx.x;
  const int tx = t & 31, ty = t >> 5;          // tx: r/16 (0..31), ty: l/2 (0..7)
  const int n = blockIdx.y;
  const int g = n >> 2, k = n & 3;
  const int l0 = blockIdx.x << 4;

  for (int i = t; i < LH2; i += 256) h2l[hsw(i)] = ws[OFF_H2 + i];

  float acc[2][16] = {};
  const float* __restrict__ xn = x + (size_t)n * WD * WD;
  const int first = tx << 4;

  for (int mc = 0; mc < WD; mc += 64) {
    __syncthreads();
    {                                          // stage x[mc..mc+63][l0..l0+15]
      int row = t >> 2;
      int c4 = (t & 3) << 2;
      float4 v = *(const float4*)(xn + (size_t)(mc + row) * WD + l0 + c4);
      *(float4*)(&bxl[row][c4]) = v;
    }
    __syncthreads();
    const int rbase = first + 512 - mc;
    float w[16];
#pragma unroll
    for (int j = 0; j < 16; ++j) w[j] = h2l[hsw(rbase + j)];
    for (int mb = 0; mb < 64; mb += 8) {
      float nh8[8];
      float2 bv8[8];
#pragma unroll
      for (int kk = 0; kk < 8; ++kk) {         // batch LDS loads (8 indep each)
        nh8[kk] = h2l[hsw(rbase - (mb + kk) - 1)];
        bv8[kk] = *(const float2*)(&bxl[mb + kk][ty << 1]);
      }
#pragma unroll
      for (int kk = 0; kk < 8; ++kk) {
        float b0 = bv8[kk].x, b1 = bv8[kk].y;
#pragma unroll
        for (int rj = 0; rj < 16; ++rj) {
          acc[0][rj] = fmaf(b0, w[rj], acc[0][rj]);
          acc[1][rj] = fmaf(b1, w[rj], acc[1][rj]);
        }
#pragma unroll
        for (int j = 15; j > 0; --j) w[j] = w[j - 1];   // renamed by unroll
        w[0] = nh8[kk];
      }
    }
  }

  // Epilogue: scatter into interleaved pk table (byte lane k, group g).
#pragma unroll
  for (int li = 0; li < 2; ++li) {
    int l = l0 + (ty << 1) + li;
    size_t rowb = ((size_t)(g * 512 + l) * 512) * 16 + (size_t)(k << 2);
#pragma unroll
    for (int j = 0; j < 15; ++j) {             // full entries s = first..first+14
      unsigned d = pkbits(acc[li][j], acc[li][j + 1]);
      *(unsigned*)(pk + rowb + (size_t)(first + j) * 16) = d;
    }
    unsigned lastp = pkbits(acc[li][15], 0.f);
    if (first + 15 == 511) {
      *(unsigned*)(pk + rowb + (size_t)511 * 16) = lastp;     // hi half must be 0
    } else {
      *(unsigned short*)(pk + rowb + (size_t)(first + 15) * 16) = (unsigned short)lastp;
    }
    if (first > 0) {                            // hi half of entry s = first-1
      unsigned fh = pkbits(acc[li][0], 0.f);
      *(unsigned short*)(pk + rowb + (size_t)(first - 1) * 16 + 2) = (unsigned short)fh;
    }
  }
}

// ---------------------------------------------------------------------------
// Backprojection v6: 1024-thread blocks (32 waves/CU = 8/SIMD), 64x64 px x
// 4 imgs, TWO angles per LDS round (4 buffers), ONE barrier per 2 angles.
// Thread: 1 i-row x 4 j (bi fma amortized). Corner tiles fully outside the
// circle skip all compute. Staging: 1 uint4 load + 1 ds_write_b128/thread.
// ---------------------------------------------------------------------------
__device__ __forceinline__ uint4 blend4(uint4 a, uint4 b, float wA, float wB) {
  unsigned r[4];
  const unsigned* pa = &a.x; const unsigned* pb = &b.x;
#pragma unroll
  for (int i = 0; i < 4; ++i) {
    half2_t ha = __builtin_bit_cast(half2_t, pa[i]);
    half2_t hb = __builtin_bit_cast(half2_t, pb[i]);
    r[i] = pkbits(fmaf((float)ha.x, wA, (float)hb.x * wB),
                  fmaf((float)ha.y, wA, (float)hb.y * wB));
  }
  return make_uint4(r[0], r[1], r[2], r[3]);
}

__device__ __forceinline__ void loadrow(const unsigned char* gb, float4 a, int s,
                                        uint4& v) {
  int ia = __float_as_int(a.w);
  v = *(const uint4*)(gb + (size_t)ia * (512 * 16) + (size_t)s * 16);
  float wB = a.z;
  if (wB != 0.f) {                       // generic angle interp (never taken, L==WD)
    int ib = ia + 1 < 511 ? ia + 1 : 511;
    uint4 u = *(const uint4*)(gb + (size_t)ib * (512 * 16) + (size_t)s * 16);
    v = blend4(v, u, 1.f - wB, wB);
  }
}

__device__ __forceinline__ void accum_angle(const uint4* __restrict__ br,
                                            float4 a, float tiv,
                                            const float* __restrict__ tjv,
                                            float hw, float acc[4][4]) {
  const float chw = a.x, shw = a.y;
  float bi = fmaf(tiv, -shw, hw);
#pragma unroll
  for (int dj = 0; dj < 4; ++dj) {
    float ry = fmaf(tjv[dj], chw, bi);
    int idx = (int)ry;                   // trunc; OOB lands in zero guards
    float w1 = ry - (float)idx;
    half2_t wpk = pkh(1.f - w1, w1);
    uint4 q = br[idx + GOFF];            // one ds_read_b128 serves 4 images
    acc[dj][0] = dot2f(q.x, wpk, acc[dj][0]);
    acc[dj][1] = dot2f(q.y, wpk, acc[dj][1]);
    acc[dj][2] = dot2f(q.z, wpk, acc[dj][2]);
    acc[dj][3] = dot2f(q.w, wpk, acc[dj][3]);
  }
}

__global__ __launch_bounds__(1024, 8) void backproj_kernel(
    const float* __restrict__ ws, const unsigned char* __restrict__ pk,
    float* __restrict__ out, int L) {
  __shared__ __align__(16) uint4 buf[2][2][GSLOTS];   // [round parity][angle][slot]
  const int t = threadIdx.x;
  const int tx = t & 15, ty = t >> 4;        // ty: 0..63 (full i of tile)
  const int j0 = (blockIdx.x & 7) << 6;
  const int i0 = (blockIdx.x >> 3) << 6;
  const int g = blockIdx.y;
  const int n0 = g << 2;

  const float tiv = t2(i0 + ty);
  float tjv[4];
#pragma unroll
  for (int a = 0; a < 4; ++a) tjv[a] = t2(j0 + tx + 16 * a);

  // Corner-tile skip: entire 64x64 tile outside the circle -> zeros, no compute.
  {
    float il = t2(i0), ih = t2(i0 + 63);
    float jl = t2(j0), jh = t2(j0 + 63);
    float mi = (il <= 0.f && ih >= 0.f) ? 0.f : fminf(fabsf(il), fabsf(ih));
    float mj = (jl <= 0.f && jh >= 0.f) ? 0.f : fminf(fabsf(jl), fabsf(jh));
    if (mi * mi + mj * mj > 1.f) {
#pragma unroll
      for (int k = 0; k < 4; ++k) {
        float* ob = out + (size_t)(n0 + k) * WD * WD + (size_t)(i0 + ty) * WD;
#pragma unroll
        for (int dj = 0; dj < 4; ++dj) ob[j0 + tx + 16 * dj] = 0.f;
      }
      return;
    }
  }

  const float4* __restrict__ angp = (const float4*)(ws + OFF_ANG);
  const unsigned char* gb = pk + (size_t)g * (512 * 512 * 16);

  for (int s = t; s < 2 * 2 * GSLOTS; s += 1024)
    ((uint4*)buf)[s] = make_uint4(0u, 0u, 0u, 0u);
  __syncthreads();                       // guards visible before first staging

  const float hw = 0.5f * (float)(WD - 1);
  float acc[4][4] = {};                  // [dj][img]

  const int sA = t & 511;                // staged slot
  const int p = t >> 9;                  // which of the round's 2 angles we stage

  float4 aA = angp[0];
  float4 aB = angp[L > 1 ? 1 : 0];
  uint4 v;
  loadrow(gb, p ? aB : aA, sA, v);

  const int rounds = (L + 1) >> 1;
  for (int r = 0; r < rounds; ++r) {
    const int rp = r & 1;
    buf[rp][p][GOFF + sA] = v;           // 1 ds_write_b128, conflict-free
    int na = 2 * r + 2, nb = 2 * r + 3;
    float4 aA2 = angp[na < L ? na : L - 1];
    float4 aB2 = angp[nb < L ? nb : L - 1];
    if (r + 1 < rounds) loadrow(gb, p ? aB2 : aA2, sA, v);   // overlap compute
    __syncthreads();                     // ONE barrier per 2 angles

    accum_angle(&buf[rp][0][0], aA, tiv, tjv, hw, acc);
    if (2 * r + 1 < L)
      accum_angle(&buf[rp][1][0], aB, tiv, tjv, hw, acc);
    aA = aA2; aB = aB2;
  }

  const float scale = (float)(3.14159265358979323846 / (2.0 * (double)L));
#pragma unroll
  for (int k = 0; k < 4; ++k) {
    float* ob = out + (size_t)(n0 + k) * WD * WD + (size_t)(i0 + ty) * WD;
#pragma unroll
    for (int dj = 0; dj < 4; ++dj) {
      float rr = tiv * tiv + tjv[dj] * tjv[dj];
      ob[j0 + tx + 16 * dj] = (rr <= 1.f) ? acc[dj][k] * scale : 0.f;
    }
  }
}

extern "C" void kernel_launch(void* const* d_in, const int* in_sizes, int n_in,
                              void* d_out, int out_size, void* d_ws, size_t ws_size,
                              hipStream_t stream) {
  const float* x = (const float*)d_in[0];
  const float* theta = (const float*)d_in[1];
  float* out = (float*)d_out;
  float* ws = (float*)d_ws;
  int L = in_sizes[1];                       // 512
  int NC = in_sizes[0] / (WD * WD);          // 32
  unsigned char* pk = (unsigned char*)(ws + OFF_PK);

  int nset = LH2 + L;
  hipLaunchKernelGGL(setup_kernel, dim3((nset + 255) / 256), dim3(256), 0, stream,
                     theta, ws, L);
  hipLaunchKernelGGL(filter_kernel, dim3(32, NC), dim3(256), 0, stream,
                     x, ws, pk);
  hipLaunchKernelGGL(backproj_kernel, dim3(64, NC / 4), dim3(1024), 0, stream,
                     ws, pk, out, L);
}